// Round 1
// baseline (6673.743 us; speedup 1.0000x reference)
//
#include <hip/hip_runtime.h>
#include <hip/hip_bf16.h>

#define D 64
#define R 128
#define BE 64            // edges per block
#define RC 32            // r-chunk staged in LDS
#define LDSS 68          // transpose-buffer stride: 16B-aligned rows, 4-way write conflict only
#define LOG2F_ 0.6931471805599453f

__device__ __forceinline__ float ssp_f(float x) {
    // shifted softplus, numerically stable
    return fmaxf(x, 0.0f) + log1pf(__expf(-fabsf(x))) - LOG2F_;
}

// Fused: f = ssp(ssp(bf@W1+b1)@W2+b2); m = nh[src]*f*eh; atomic scatter-add to s[dst]; cnt[dst]++
__global__ __launch_bounds__(256, 2)
void schnet_edge_kernel(const float* __restrict__ bf, const float* __restrict__ eh,
                        const float* __restrict__ nh, const int* __restrict__ src,
                        const int* __restrict__ dst,
                        const float* __restrict__ W1, const float* __restrict__ b1,
                        const float* __restrict__ W2, const float* __restrict__ b2,
                        float* __restrict__ sacc, float* __restrict__ cnt, int E)
{
    __shared__ float sW1[R * D];        // 32 KB, [r][d]
    __shared__ float sW2[D * D];        // 16 KB, [k][d]
    __shared__ float sB1[D];
    __shared__ float sB2[D];
    __shared__ float sBfT[RC * LDSS];   // bf chunk, transposed [r][e]
    __shared__ float sFT[D * LDSS];     // ssp(f1), transposed [k][e]

    const int tid = threadIdx.x;
    const int ebase = blockIdx.x * BE;

    for (int i = tid; i < R * D / 4; i += 256)
        reinterpret_cast<float4*>(sW1)[i] = reinterpret_cast<const float4*>(W1)[i];
    for (int i = tid; i < D * D / 4; i += 256)
        reinterpret_cast<float4*>(sW2)[i] = reinterpret_cast<const float4*>(W2)[i];
    if (tid < D) { sB1[tid] = b1[tid]; sB2[tid] = b2[tid]; }

    const int dg = tid & 15;        // feature group
    const int eg = tid >> 4;        // edge group
    const int d0 = dg * 4;
    const int e0 = eg * 4;

    float acc1[4][4] = {};          // [local edge j][feature i]

    // GEMM1: [64 edges,128] @ [128,64], K chunked by RC
    for (int rc = 0; rc < R; rc += RC) {
        __syncthreads();            // protect sBfT reuse (also orders weight loads on first iter)
        {
            const int r = tid & 31;
            const int eb = tid >> 5;
            #pragma unroll
            for (int p = 0; p < 8; ++p) {
                const int e = eb + 8 * p;
                const int eglob = ebase + e;
                float v = (eglob < E) ? bf[(size_t)eglob * R + rc + r] : 0.0f;
                sBfT[r * LDSS + e] = v;
            }
        }
        __syncthreads();
        #pragma unroll
        for (int r = 0; r < RC; ++r) {
            const float4 bv = *reinterpret_cast<const float4*>(&sBfT[r * LDSS + e0]);
            const float4 wv = *reinterpret_cast<const float4*>(&sW1[(rc + r) * D + d0]);
            const float bvv[4] = {bv.x, bv.y, bv.z, bv.w};
            const float wvv[4] = {wv.x, wv.y, wv.z, wv.w};
            #pragma unroll
            for (int j = 0; j < 4; ++j)
                #pragma unroll
                for (int i = 0; i < 4; ++i)
                    acc1[j][i] += bvv[j] * wvv[i];
        }
    }

    // ssp(f1 + b1) -> transposed LDS for GEMM2
    #pragma unroll
    for (int j = 0; j < 4; ++j)
        #pragma unroll
        for (int i = 0; i < 4; ++i)
            sFT[(d0 + i) * LDSS + (e0 + j)] = ssp_f(acc1[j][i] + sB1[d0 + i]);
    __syncthreads();

    float acc2[4][4] = {};
    #pragma unroll
    for (int k = 0; k < D; ++k) {
        const float4 fv = *reinterpret_cast<const float4*>(&sFT[k * LDSS + e0]);
        const float4 wv = *reinterpret_cast<const float4*>(&sW2[k * D + d0]);
        const float fvv[4] = {fv.x, fv.y, fv.z, fv.w};
        const float wvv[4] = {wv.x, wv.y, wv.z, wv.w};
        #pragma unroll
        for (int j = 0; j < 4; ++j)
            #pragma unroll
            for (int i = 0; i < 4; ++i)
                acc2[j][i] += fvv[j] * wvv[i];
    }

    // gate with eh, gather nh[src], scatter-add to s[dst]
    #pragma unroll
    for (int j = 0; j < 4; ++j) {
        const int e = ebase + e0 + j;
        if (e < E) {
            const int sj = src[e];
            const int dj = dst[e];
            const float4 ehv = *reinterpret_cast<const float4*>(&eh[(size_t)e * D + d0]);
            const float4 nv  = *reinterpret_cast<const float4*>(&nh[(size_t)sj * D + d0]);
            const float m0 = ssp_f(acc2[j][0] + sB2[d0 + 0]) * ehv.x * nv.x;
            const float m1 = ssp_f(acc2[j][1] + sB2[d0 + 1]) * ehv.y * nv.y;
            const float m2 = ssp_f(acc2[j][2] + sB2[d0 + 2]) * ehv.z * nv.z;
            const float m3 = ssp_f(acc2[j][3] + sB2[d0 + 3]) * ehv.w * nv.w;
            float* dstp = &sacc[(size_t)dj * D + d0];
            atomicAdd(dstp + 0, m0);
            atomicAdd(dstp + 1, m1);
            atomicAdd(dstp + 2, m2);
            atomicAdd(dstp + 3, m3);
        }
    }
    if (dg == 0) {
        #pragma unroll
        for (int j = 0; j < 4; ++j) {
            const int e = ebase + e0 + j;
            if (e < E) atomicAdd(&cnt[dst[e]], 1.0f);
        }
    }
}

// agg = where(cnt>0, s/cnt, 0); out = ssp(ssp(agg@W3+b3)@W4+b4)
__global__ __launch_bounds__(256, 2)
void schnet_node_kernel(const float* __restrict__ sacc, const float* __restrict__ cnt,
                        const float* __restrict__ W3, const float* __restrict__ b3,
                        const float* __restrict__ W4, const float* __restrict__ b4,
                        float* __restrict__ out, int N)
{
    __shared__ float sW3[D * D];
    __shared__ float sW4[D * D];
    __shared__ float sB3[D];
    __shared__ float sB4[D];
    __shared__ float sT[D * LDSS];   // aggT, then reused as hT

    const int tid = threadIdx.x;
    const int nbase = blockIdx.x * 64;

    for (int i = tid; i < D * D / 4; i += 256) {
        reinterpret_cast<float4*>(sW3)[i] = reinterpret_cast<const float4*>(W3)[i];
        reinterpret_cast<float4*>(sW4)[i] = reinterpret_cast<const float4*>(W4)[i];
    }
    if (tid < D) { sB3[tid] = b3[tid]; sB4[tid] = b4[tid]; }

    // stage agg (scatter-mean) transposed into sT
    #pragma unroll
    for (int p = 0; p < 4; ++p) {
        const int f = tid + 256 * p;   // float4 index over 64x16
        const int n = f >> 4;
        const int dq = f & 15;
        const int ng = nbase + n;
        float4 v = make_float4(0.f, 0.f, 0.f, 0.f);
        if (ng < N) {
            v = *reinterpret_cast<const float4*>(&sacc[(size_t)ng * D + dq * 4]);
            const float c = cnt[ng];
            const float inv = (c > 0.0f) ? 1.0f / c : 0.0f;
            v.x *= inv; v.y *= inv; v.z *= inv; v.w *= inv;
        }
        sT[(dq * 4 + 0) * LDSS + n] = v.x;
        sT[(dq * 4 + 1) * LDSS + n] = v.y;
        sT[(dq * 4 + 2) * LDSS + n] = v.z;
        sT[(dq * 4 + 3) * LDSS + n] = v.w;
    }
    __syncthreads();

    const int dg = tid & 15;
    const int ng4 = tid >> 4;
    const int d0 = dg * 4;
    const int n0 = ng4 * 4;

    float acc3[4][4] = {};
    #pragma unroll
    for (int k = 0; k < D; ++k) {
        const float4 av = *reinterpret_cast<const float4*>(&sT[k * LDSS + n0]);
        const float4 wv = *reinterpret_cast<const float4*>(&sW3[k * D + d0]);
        const float avv[4] = {av.x, av.y, av.z, av.w};
        const float wvv[4] = {wv.x, wv.y, wv.z, wv.w};
        #pragma unroll
        for (int j = 0; j < 4; ++j)
            #pragma unroll
            for (int i = 0; i < 4; ++i)
                acc3[j][i] += avv[j] * wvv[i];
    }
    float h[4][4];
    #pragma unroll
    for (int j = 0; j < 4; ++j)
        #pragma unroll
        for (int i = 0; i < 4; ++i)
            h[j][i] = ssp_f(acc3[j][i] + sB3[d0 + i]);
    __syncthreads();                 // all reads of aggT done
    #pragma unroll
    for (int j = 0; j < 4; ++j)
        #pragma unroll
        for (int i = 0; i < 4; ++i)
            sT[(d0 + i) * LDSS + (n0 + j)] = h[j][i];
    __syncthreads();

    float acc4[4][4] = {};
    #pragma unroll
    for (int k = 0; k < D; ++k) {
        const float4 hv = *reinterpret_cast<const float4*>(&sT[k * LDSS + n0]);
        const float4 wv = *reinterpret_cast<const float4*>(&sW4[k * D + d0]);
        const float hvv[4] = {hv.x, hv.y, hv.z, hv.w};
        const float wvv[4] = {wv.x, wv.y, wv.z, wv.w};
        #pragma unroll
        for (int j = 0; j < 4; ++j)
            #pragma unroll
            for (int i = 0; i < 4; ++i)
                acc4[j][i] += hvv[j] * wvv[i];
    }

    #pragma unroll
    for (int j = 0; j < 4; ++j) {
        const int ng = nbase + n0 + j;
        if (ng < N) {
            float4 o;
            o.x = ssp_f(acc4[j][0] + sB4[d0 + 0]);
            o.y = ssp_f(acc4[j][1] + sB4[d0 + 1]);
            o.z = ssp_f(acc4[j][2] + sB4[d0 + 2]);
            o.w = ssp_f(acc4[j][3] + sB4[d0 + 3]);
            *reinterpret_cast<float4*>(&out[(size_t)ng * D + d0]) = o;
        }
    }
}

extern "C" void kernel_launch(void* const* d_in, const int* in_sizes, int n_in,
                              void* d_out, int out_size, void* d_ws, size_t ws_size,
                              hipStream_t stream)
{
    const float* bf = (const float*)d_in[0];
    const float* eh = (const float*)d_in[1];
    const float* nh = (const float*)d_in[2];
    const int*   src = (const int*)d_in[3];
    const int*   dst = (const int*)d_in[4];
    const float* W1 = (const float*)d_in[5];
    const float* b1 = (const float*)d_in[6];
    const float* W2 = (const float*)d_in[7];
    const float* b2 = (const float*)d_in[8];
    const float* W3 = (const float*)d_in[9];
    const float* b3 = (const float*)d_in[10];
    const float* W4 = (const float*)d_in[11];
    const float* b4 = (const float*)d_in[12];

    const int E = in_sizes[3];           // src count
    const int N = in_sizes[2] / D;       // nh count / D

    float* sacc = (float*)d_ws;          // [N, D] scatter-sum
    float* cnt  = sacc + (size_t)N * D;  // [N] in-degree
    hipMemsetAsync(d_ws, 0, ((size_t)N * D + N) * sizeof(float), stream);

    const int gridE = (E + BE - 1) / BE;
    schnet_edge_kernel<<<gridE, 256, 0, stream>>>(bf, eh, nh, src, dst,
                                                  W1, b1, W2, b2, sacc, cnt, E);
    const int gridN = (N + 63) / 64;
    schnet_node_kernel<<<gridN, 256, 0, stream>>>(sacc, cnt, W3, b3, W4, b4,
                                                  (float*)d_out, N);
}